// Round 11
// baseline (1234.097 us; speedup 1.0000x reference)
//
#include <hip/hip_runtime.h>
#include <math.h>

#define NN 50000
#define EE 800000
#define HH 4
#define CC 64
#define DE 16
#define GG 64
#define HC 256          // H*C
#define NEG 0.2f
#define EPSV 1e-5f
#define NB 196          // scan blocks: 196*256 = 50176 >= NN
#define SB 16           // stats sub-blocks per group
#define MB 1280         // mega-kernel blocks: 5 blocks/CU x 256 CUs (co-resident)

typedef __attribute__((ext_vector_type(8))) short short8;
typedef __attribute__((ext_vector_type(4))) float f32x4;
typedef __attribute__((ext_vector_type(2))) float f32x2;

__device__ __forceinline__ unsigned short f2bf(float f) {
  unsigned int x = __float_as_uint(f);
  unsigned int r = (x + 0x7fff + ((x >> 16) & 1)) >> 16;  // round-nearest-even
  return (unsigned short)r;
}
__device__ __forceinline__ float lrelu(float a) {
  return fmaxf(a, 0.f) + NEG * fminf(a, 0.f);
}

// Device-wide barrier: generation counter + arrive count in bar[0..1].
// All MB blocks are co-resident by construction (__launch_bounds__(256,5),
// grid = 5*256), so spinning is deadlock-free. One O(1) barrier per phase —
// NOT R9's serialized 196-deep lookback chain.
__device__ __forceinline__ void grid_sync(unsigned int* bar) {
  __syncthreads();
  if (threadIdx.x == 0) {
    __threadfence();                              // release my writes
    unsigned g = atomicAdd(&bar[1], 0u);          // read generation FIRST
    unsigned old = atomicAdd(&bar[0], 1u);
    if (old == (unsigned)(MB - 1)) {
      atomicExch(&bar[0], 0u);                    // reset count
      __threadfence();
      atomicAdd(&bar[1], 1u);                     // release waiters
    } else {
      while (atomicAdd(&bar[1], 0u) == g) __builtin_amdgcn_s_sleep(1);
    }
    __threadfence();                              // acquire others' writes
  }
  __syncthreads();
}

// K0: blocks 0..63: Wbt transpose. block 64: v_edge + zero barrier state.
// blocks 65..260: zero hist.
__global__ __launch_bounds__(256) void k_prep(
    const float* __restrict__ W, const float* __restrict__ We,
    const float* __restrict__ ae_, unsigned short* __restrict__ Wbt,
    float* __restrict__ v_edge, int* __restrict__ hist,
    unsigned int* __restrict__ bar) {
  int b = blockIdx.x, t = threadIdx.x;
  if (b < 64) {
    Wbt[(size_t)t * 64 + b] = f2bf(W[b * HC + (t & 3) * 64 + (t >> 2)]);
  } else if (b == 64) {
    if (t < DE * HH) {
      int d = t >> 2, h = t & 3;
      float s = 0.f;
      for (int c = 0; c < CC; ++c)
        s += We[d * HC + h * CC + c] * ae_[h * CC + c];
      v_edge[t] = s;
    } else if (t < DE * HH + 2) {
      bar[t - DE * HH] = 0u;
    }
  } else {
    int idx = (b - 65) * 256 + t;
    if (idx < NN) hist[idx] = 0;
  }
}

#define EDGE_STEP(rn, un)                                              \
    {                                                                  \
      f32x2 ta, tb, xa, xb2;                                           \
      ta.x = __uint_as_float(rn.x << 16);                              \
      ta.y = __uint_as_float(rn.x & 0xffff0000u);                      \
      tb.x = __uint_as_float(rn.y << 16);                              \
      tb.y = __uint_as_float(rn.y & 0xffff0000u);                      \
      xa.x = __uint_as_float(un.x << 16);                              \
      xa.y = __uint_as_float(un.x & 0xffff0000u);                      \
      xb2.x = __uint_as_float(un.y << 16);                             \
      xb2.y = __uint_as_float(un.y & 0xffff0000u);                     \
      d01 += ta;                                                       \
      d23 += tb;                                                       \
      acc01 += ta * xa;                                                \
      acc23 += tb * xb2;                                               \
    }

// MEGA: xproj+hist -> scanA -> scanC -> edge_perm -> gat -> post1 -> final,
// one dispatch, 6 grid barriers. Each phase body is the R10 kernel verbatim
// with blockIdx replaced by a grid-stride virtual block id.
__global__ __launch_bounds__(256, 5) void k_mega(
    const float* __restrict__ node, const unsigned short* __restrict__ Wbt,
    const float* __restrict__ att_src, const float* __restrict__ att_dst,
    unsigned short* __restrict__ x16, float* __restrict__ a_src,
    float* __restrict__ a_dst, const int* __restrict__ ei,
    int* __restrict__ hist, int* __restrict__ bsum, int* __restrict__ ptr,
    int* __restrict__ cursor, const float* __restrict__ eatt,
    const float* __restrict__ v_edge, uint4* __restrict__ recs,
    uint2* __restrict__ t_lin, float* __restrict__ out_acc,
    float* __restrict__ rinv, const int* __restrict__ batch,
    const float* __restrict__ bias, float* __restrict__ p1,
    float* __restrict__ p2, int* __restrict__ gcnt,
    const float* __restrict__ gns, const float* __restrict__ gnw,
    const float* __restrict__ gnb, float* __restrict__ y,
    float* __restrict__ att_out, unsigned int* __restrict__ bar) {
  __shared__ unsigned short xs[16][260];
  __shared__ float lss[4][16][4], lsd[4][16][4];
  __shared__ int sA[256], sB[256];
  __shared__ float vsh[DE * HH];
  __shared__ float l1[4][64], l2[4][64];
  const int tid = threadIdx.x;
  const int bid = blockIdx.x;
  const int lane = tid & 63;
  const int w = tid >> 6;

  // ---------- P0: xproj + fused hist ----------
  {
    int m = lane & 15, quad = lane >> 4;
    for (int tile = bid; tile < NN / 16; tile += MB) {
      { int e = tile * 256 + tid; atomicAdd(&hist[ei[EE + e]], 1); }
      int m0 = tile * 16;
      const float* arow = node + (size_t)(m0 + m) * CC + quad * 8;
      float4 af0 = *(const float4*)(arow);
      float4 af1 = *(const float4*)(arow + 4);
      float4 af2 = *(const float4*)(arow + 32);
      float4 af3 = *(const float4*)(arow + 36);
      short8 a0 = {(short)f2bf(af0.x), (short)f2bf(af0.y), (short)f2bf(af0.z),
                   (short)f2bf(af0.w), (short)f2bf(af1.x), (short)f2bf(af1.y),
                   (short)f2bf(af1.z), (short)f2bf(af1.w)};
      short8 a1 = {(short)f2bf(af2.x), (short)f2bf(af2.y), (short)f2bf(af2.z),
                   (short)f2bf(af2.w), (short)f2bf(af3.x), (short)f2bf(af3.y),
                   (short)f2bf(af3.z), (short)f2bf(af3.w)};
      float sa[4] = {0, 0, 0, 0}, sd[4] = {0, 0, 0, 0};
#pragma unroll
      for (int i = 0; i < 4; ++i) {
        int tc = (w * 4 + i) * 16 + m;
        const unsigned short* bp = Wbt + (size_t)tc * 64 + quad * 8;
        short8 b0 = *(const short8*)(bp);
        short8 b1 = *(const short8*)(bp + 32);
        f32x4 acc = {0.f, 0.f, 0.f, 0.f};
        acc = __builtin_amdgcn_mfma_f32_16x16x32_bf16(a0, b0, acc, 0, 0, 0);
        acc = __builtin_amdgcn_mfma_f32_16x16x32_bf16(a1, b1, acc, 0, 0, 0);
        float us_t = att_src[(tc & 3) * CC + (tc >> 2)];
        float ud_t = att_dst[(tc & 3) * CC + (tc >> 2)];
#pragma unroll
        for (int r = 0; r < 4; ++r) {
          xs[quad * 4 + r][tc] = f2bf(acc[r]);
          sa[r] += acc[r] * us_t;
          sd[r] += acc[r] * ud_t;
        }
      }
#pragma unroll
      for (int r = 0; r < 4; ++r) {
        sa[r] += __shfl_xor(sa[r], 4);
        sa[r] += __shfl_xor(sa[r], 8);
        sd[r] += __shfl_xor(sd[r], 4);
        sd[r] += __shfl_xor(sd[r], 8);
      }
      if ((lane & 12) == 0) {
#pragma unroll
        for (int r = 0; r < 4; ++r) {
          lss[w][quad * 4 + r][lane & 3] = sa[r];
          lsd[w][quad * 4 + r][lane & 3] = sd[r];
        }
      }
      __syncthreads();
      if (tid < 64) {
        int row = tid >> 2, h = tid & 3;
        a_src[(size_t)(m0 + row) * 4 + h] =
            lss[0][row][h] + lss[1][row][h] + lss[2][row][h] + lss[3][row][h];
        a_dst[(size_t)(m0 + row) * 4 + h] =
            lsd[0][row][h] + lsd[1][row][h] + lsd[2][row][h] + lsd[3][row][h];
      }
      {
        int row = tid >> 4, seg = tid & 15;
        const unsigned short* xr = &xs[0][0] + row * 260 + seg * 16;
        uint2 lo = *(const uint2*)(xr);
        uint2 hi = *(const uint2*)(xr + 4);
        uint4 o;
        o.x = lo.x; o.y = lo.y; o.z = hi.x; o.w = hi.y;
        uint4* xg = (uint4*)(x16 + (size_t)m0 * HC);
        xg[row * 32 + seg * 2] = o;
        uint2 lo2 = *(const uint2*)(xr + 8);
        uint2 hi2 = *(const uint2*)(xr + 12);
        uint4 o2;
        o2.x = lo2.x; o2.y = lo2.y; o2.z = hi2.x; o2.w = hi2.y;
        xg[row * 32 + seg * 2 + 1] = o2;
      }
      __syncthreads();  // protect xs/lss reuse across grid-stride iterations
    }
  }
  grid_sync(bar);

  // ---------- P1: scanA ----------
  for (int c = bid; c < NB; c += MB) {
    int idx = c * 256 + tid;
    sA[tid] = (idx < NN) ? hist[idx] : 0;
    __syncthreads();
    for (int d = 128; d; d >>= 1) {
      if (tid < d) sA[tid] += sA[tid + d];
      __syncthreads();
    }
    if (tid == 0) bsum[c] = sA[0];
    __syncthreads();
  }
  grid_sync(bar);

  // ---------- P2: scanC ----------
  for (int c = bid; c < NB; c += MB) {
    sB[tid] = (tid < NB) ? bsum[tid] : 0;
    __syncthreads();
    for (int d = 1; d < 256; d <<= 1) {
      int u = (tid >= d) ? sB[tid - d] : 0;
      __syncthreads();
      sB[tid] += u;
      __syncthreads();
    }
    int boffv = sB[c] - bsum[c];
    if (c == NB - 1 && tid == 0) ptr[NN] = sB[NB - 1];
    int idx = c * 256 + tid;
    int v = (idx < NN) ? hist[idx] : 0;
    sA[tid] = v;
    __syncthreads();
    for (int d = 1; d < 256; d <<= 1) {
      int u = (tid >= d) ? sA[tid - d] : 0;
      __syncthreads();
      sA[tid] += u;
      __syncthreads();
    }
    if (idx < NN) {
      int p = boffv + sA[tid] - v;
      ptr[idx] = p;
      cursor[idx] = p;
    }
    __syncthreads();
  }
  grid_sync(bar);

  // ---------- P3: edge_perm (chunked 2 edges/thread, atomics late) ----------
  if (tid < DE * HH) vsh[tid] = v_edge[tid];
  __syncthreads();
  for (int vb = bid; vb < (EE + 511) / 512; vb += MB) {
    int e0 = vb * 512 + tid;            // always < EE (1562*512+255 < 800000)
    int e1 = e0 + 256;
    bool has1 = (e1 < EE);
    int e1c = has1 ? e1 : e0;
    int sn0 = ei[e0], dn0 = ei[EE + e0];
    int sn1 = ei[e1c], dn1 = ei[EE + e1c];
    float4 as0 = *(const float4*)(a_src + (size_t)sn0 * 4);
    float4 ad0 = *(const float4*)(a_dst + (size_t)dn0 * 4);
    float4 as1 = *(const float4*)(a_src + (size_t)sn1 * 4);
    float4 ad1 = *(const float4*)(a_dst + (size_t)dn1 * 4);
    const float4* ea0 = (const float4*)(eatt + (size_t)e0 * DE);
    const float4* ea1 = (const float4*)(eatt + (size_t)e1c * DE);
    float ae0[4] = {0, 0, 0, 0}, ae1[4] = {0, 0, 0, 0};
#pragma unroll
    for (int dd = 0; dd < 4; ++dd) {
      float4 ev0 = ea0[dd];
      float4 ev1 = ea1[dd];
      float evs0[4] = {ev0.x, ev0.y, ev0.z, ev0.w};
      float evs1[4] = {ev1.x, ev1.y, ev1.z, ev1.w};
#pragma unroll
      for (int jj = 0; jj < 4; ++jj) {
        int d = dd * 4 + jj;
#pragma unroll
        for (int h = 0; h < 4; ++h) {
          ae0[h] += evs0[jj] * vsh[d * 4 + h];
          ae1[h] += evs1[jj] * vsh[d * 4 + h];
        }
      }
    }
    float p0 = __expf(lrelu(as0.x + ad0.x + ae0[0]));
    float p1v = __expf(lrelu(as0.y + ad0.y + ae0[1]));
    float p2v = __expf(lrelu(as0.z + ad0.z + ae0[2]));
    float p3 = __expf(lrelu(as0.w + ad0.w + ae0[3]));
    float q0 = __expf(lrelu(as1.x + ad1.x + ae1[0]));
    float q1 = __expf(lrelu(as1.y + ad1.y + ae1[1]));
    float q2 = __expf(lrelu(as1.z + ad1.z + ae1[2]));
    float q3 = __expf(lrelu(as1.w + ad1.w + ae1[3]));
    uint2 tl0, tl1;
    tl0.x = (unsigned int)f2bf(p0) | ((unsigned int)f2bf(p1v) << 16);
    tl0.y = (unsigned int)f2bf(p2v) | ((unsigned int)f2bf(p3) << 16);
    tl1.x = (unsigned int)f2bf(q0) | ((unsigned int)f2bf(q1) << 16);
    tl1.y = (unsigned int)f2bf(q2) | ((unsigned int)f2bf(q3) << 16);
    t_lin[e0] = tl0;
    if (has1) t_lin[e1] = tl1;
    int pos0 = atomicAdd(&cursor[dn0], 1);
    int pos1 = has1 ? atomicAdd(&cursor[dn1], 1) : 0;
    uint4 rec0;
    rec0.x = tl0.x; rec0.y = tl0.y;
    rec0.z = (unsigned int)sn0 << 9;  // byte offset: sn * HC * 2
    rec0.w = (unsigned int)e0;
    recs[pos0] = rec0;
    if (has1) {
      uint4 rec1;
      rec1.x = tl1.x; rec1.y = tl1.y;
      rec1.z = (unsigned int)sn1 << 9;
      rec1.w = (unsigned int)e1;
      recs[pos1] = rec1;
    }
  }
  grid_sync(bar);

  // ---------- P4: gat ----------
  for (int vb = bid; vb < NN / 4; vb += MB) {
    int v = vb * 4 + w;
    int start = __builtin_amdgcn_readfirstlane(ptr[v]);
    int end = __builtin_amdgcn_readfirstlane(ptr[v + 1]);
    f32x2 d01 = {0.f, 0.f}, d23 = {0.f, 0.f};
    f32x2 acc01 = {0.f, 0.f}, acc23 = {0.f, 0.f};
    const char* xbase = (const char*)x16;
    unsigned int lane8 = (unsigned int)lane * 8u;
    int j = start;
#pragma unroll 2
    for (; j + 4 <= end; j += 4) {
      uint4 r0 = recs[j];
      uint4 r1 = recs[j + 1];
      uint4 r2 = recs[j + 2];
      uint4 r3 = recs[j + 3];
      uint2 u0 = *(const uint2*)(xbase + (r0.z + lane8));
      uint2 u1 = *(const uint2*)(xbase + (r1.z + lane8));
      uint2 u2 = *(const uint2*)(xbase + (r2.z + lane8));
      uint2 u3 = *(const uint2*)(xbase + (r3.z + lane8));
      EDGE_STEP(r0, u0)
      EDGE_STEP(r1, u1)
      EDGE_STEP(r2, u2)
      EDGE_STEP(r3, u3)
    }
    for (; j < end; ++j) {
      uint4 rec = recs[j];
      uint2 u = *(const uint2*)(xbase + (rec.z + lane8));
      EDGE_STEP(rec, u)
    }
    float r0 = 1.f / (d01.x + 1e-16f), r1 = 1.f / (d01.y + 1e-16f);
    float r2 = 1.f / (d23.x + 1e-16f), r3 = 1.f / (d23.y + 1e-16f);
    out_acc[(size_t)v * CC + lane] =
        0.25f * (r0 * acc01.x + r1 * acc01.y + r2 * acc23.x + r3 * acc23.y);
    if (lane == 0)
      *(float4*)(rinv + (size_t)v * 4) = make_float4(r0, r1, r2, r3);
  }
  grid_sync(bar);

  // ---------- P5: post1 (statsA + att) ----------
  for (int b = bid; b < GG * SB + (EE + 255) / 256; b += MB) {
    if (b < GG * SB) {
      int g = b / SB, sb = b % SB;
      int lo = 0, hi = NN;
      while (lo < hi) {
        int mid = (lo + hi) >> 1;
        if (batch[mid] < g) lo = mid + 1; else hi = mid;
      }
      int start = lo;
      hi = NN;
      while (lo < hi) {
        int mid = (lo + hi) >> 1;
        if (batch[mid] < g + 1) lo = mid + 1; else hi = mid;
      }
      int end = lo;
      int cnt = end - start;
      if (sb == 0 && tid == 0) gcnt[g] = cnt;
      int chunk = (cnt + SB - 1) / SB;
      int c0 = start + sb * chunk;
      int c1 = min(c0 + chunk, end);
      float bv = bias[lane];
      float s1 = 0.f, s2 = 0.f;
      for (int n = c0 + w; n < c1; n += 4) {
        float v = out_acc[(size_t)n * CC + lane] + bv;
        s1 += v;
        s2 += v * v;
      }
      l1[w][lane] = s1;
      l2[w][lane] = s2;
      __syncthreads();
      if (w == 0) {
        s1 = l1[0][lane] + l1[1][lane] + l1[2][lane] + l1[3][lane];
        s2 = l2[0][lane] + l2[1][lane] + l2[2][lane] + l2[3][lane];
        p1[(size_t)(g * SB + sb) * 64 + lane] = s1;
        p2[(size_t)(g * SB + sb) * 64 + lane] = s2;
      }
      __syncthreads();
    } else {
      int e = (b - GG * SB) * 256 + tid;
      if (e < EE) {
        uint2 tl = t_lin[e];
        int dn = ei[EE + e];
        float4 r = *(const float4*)(rinv + (size_t)dn * 4);
        float t0 = __uint_as_float(tl.x << 16);
        float t1 = __uint_as_float(tl.x & 0xffff0000u);
        float t2 = __uint_as_float(tl.y << 16);
        float t3 = __uint_as_float(tl.y & 0xffff0000u);
        *(float4*)(att_out + (size_t)e * 4) =
            make_float4(t0 * r.x, t1 * r.y, t2 * r.z, t3 * r.w);
      }
    }
  }
  grid_sync(bar);

  // ---------- P6: final (statsB fused) ----------
  for (int vb = bid; vb < NN / 4; vb += MB) {
    int n = vb * 4 + w;
    int g = batch[n];
    float s1 = 0.f, s2 = 0.f;
#pragma unroll
    for (int sb = 0; sb < SB; ++sb) {
      s1 += p1[(size_t)(g * SB + sb) * 64 + lane];
      s2 += p2[(size_t)(g * SB + sb) * 64 + lane];
    }
    float c = fmaxf((float)gcnt[g], 1.0f);
    float mean = s1 / c;
    float ms = mean * gns[lane];
    float var = s2 / c - 2.f * ms * mean + ms * ms;
    float istd = rsqrtf(var + EPSV);
    float v = out_acc[(size_t)n * CC + lane] + bias[lane];
    float o = (v - ms) * istd;
    float r = gnw[lane] * o + gnb[lane];
    y[(size_t)n * CC + lane] = fmaxf(r, 0.0f);
  }
}

#undef EDGE_STEP

extern "C" void kernel_launch(void* const* d_in, const int* in_sizes, int n_in,
                              void* d_out, int out_size, void* d_ws, size_t ws_size,
                              hipStream_t stream) {
  const float* node = (const float*)d_in[0];
  const int* ei = (const int*)d_in[1];
  const float* eatt = (const float*)d_in[2];
  const int* batch = (const int*)d_in[3];
  const float* W = (const float*)d_in[4];
  const float* We = (const float*)d_in[5];
  const float* att_src = (const float*)d_in[6];
  const float* att_dst = (const float*)d_in[7];
  const float* att_edge = (const float*)d_in[8];
  const float* bias = (const float*)d_in[9];
  const float* gnw = (const float*)d_in[10];
  const float* gnb = (const float*)d_in[11];
  const float* gns = (const float*)d_in[12];

  float* ws = (float*)d_ws;
  size_t off = 0;
  uint4* recs = (uint4*)(ws + off);  off += (size_t)EE * 4;  // 12.8 MB
  float* a_src = ws + off;    off += (size_t)NN * HH;
  float* a_dst = ws + off;    off += (size_t)NN * HH;
  float* v_edge = ws + off;   off += 64;
  float* out_acc = ws + off;  off += (size_t)NN * CC;
  float* rinv = ws + off;     off += (size_t)NN * HH;     // 0.8 MB
  float* p1 = ws + off;       off += (size_t)GG * SB * 64; // 256 KB
  float* p2 = ws + off;       off += (size_t)GG * SB * 64; // 256 KB
  uint2* t_lin = (uint2*)(ws + off);
  off += (size_t)EE * 2;                                  // 6.4 MB
  unsigned short* x16 = (unsigned short*)(ws + off);
  off += (size_t)NN * HC / 2;                             // 12.8M ushort
  unsigned short* Wbt = (unsigned short*)(ws + off);
  off += (size_t)CC * HC / 2;                             // 16K ushort
  int* iws = (int*)(ws + off);
  size_t ioff = 0;
  int* hist = iws + ioff;     ioff += NN;
  int* ptr = iws + ioff;      ioff += NN + 1;
  int* cursor = iws + ioff;   ioff += NN;
  int* bsum = iws + ioff;     ioff += NB;
  int* gcnt = iws + ioff;     ioff += GG;
  unsigned int* bar = (unsigned int*)(iws + ioff); ioff += 2;

  float* y_out = (float*)d_out;
  float* att_out = (float*)d_out + (size_t)NN * CC;

  // 2 dispatches (was 8). ~8us gap per removed dispatch boundary (measured
  // in R8: 4 fewer dispatches -> -32us).
  k_prep<<<261, 256, 0, stream>>>(W, We, att_edge, Wbt, v_edge, hist, bar);
  k_mega<<<MB, 256, 0, stream>>>(node, Wbt, att_src, att_dst, x16, a_src,
                                 a_dst, ei, hist, bsum, ptr, cursor, eatt,
                                 v_edge, recs, t_lin, out_acc, rinv, batch,
                                 bias, p1, p2, gcnt, gns, gnw, gnb, y_out,
                                 att_out, bar);
}

// Round 12
// 875.806 us; speedup vs baseline: 1.4091x; 1.4091x over previous
//
#include <hip/hip_runtime.h>
#include <math.h>

#define NN 50000
#define EE 800000
#define HH 4
#define CC 64
#define DE 16
#define GG 64
#define HC 256          // H*C
#define NEG 0.2f
#define EPSV 1e-5f
#define NB 196          // scan blocks: 196*256 = 50176 >= NN
#define SB 16           // stats sub-blocks per group
#define MB 1280         // mega-kernel blocks: 5 blocks/CU x 256 CUs (co-resident)

typedef __attribute__((ext_vector_type(8))) short short8;
typedef __attribute__((ext_vector_type(4))) float f32x4;
typedef __attribute__((ext_vector_type(2))) float f32x2;

__device__ __forceinline__ unsigned short f2bf(float f) {
  unsigned int x = __float_as_uint(f);
  unsigned int r = (x + 0x7fff + ((x >> 16) & 1)) >> 16;  // round-nearest-even
  return (unsigned short)r;
}
__device__ __forceinline__ float lrelu(float a) {
  return fmaxf(a, 0.f) + NEG * fminf(a, 0.f);
}

// Device-wide barrier, cooperative-groups style. R11's version polled with an
// atomic RMW on the SAME cache line as the arrival counter -> 1280 pollers
// ping-ponged exclusive ownership and arrivals queued behind them (~150us per
// barrier, WRITE_SIZE +125MB). Fix: (1) count and generation on SEPARATE
// 128B lines; (2) poll with a READ-ONLY device-scope load (no ownership);
// (3) s_sleep(16) backoff; (4) release via device-scope release store.
// All MB blocks are co-resident (__launch_bounds__(256,5), grid = 5*256).
__device__ __forceinline__ void grid_sync(unsigned int* bar) {
  __syncthreads();
  if (threadIdx.x == 0) {
    unsigned g = __hip_atomic_load(&bar[32], __ATOMIC_RELAXED,
                                   __HIP_MEMORY_SCOPE_AGENT);
    __threadfence();  // release this block's phase writes
    unsigned old = __hip_atomic_fetch_add(&bar[0], 1u, __ATOMIC_ACQ_REL,
                                          __HIP_MEMORY_SCOPE_AGENT);
    if (old == (unsigned)(MB - 1)) {
      __hip_atomic_store(&bar[0], 0u, __ATOMIC_RELAXED,
                         __HIP_MEMORY_SCOPE_AGENT);
      __hip_atomic_store(&bar[32], g + 1u, __ATOMIC_RELEASE,
                         __HIP_MEMORY_SCOPE_AGENT);  // orders the reset before
    } else {
      while (__hip_atomic_load(&bar[32], __ATOMIC_RELAXED,
                               __HIP_MEMORY_SCOPE_AGENT) == g)
        __builtin_amdgcn_s_sleep(16);
    }
    __threadfence();  // acquire other blocks' phase writes
  }
  __syncthreads();
}

// K0: blocks 0..63: Wbt transpose. block 64: v_edge + zero barrier state
// (64 words: count @0, gen @32, padding). blocks 65..260: zero hist.
__global__ __launch_bounds__(256) void k_prep(
    const float* __restrict__ W, const float* __restrict__ We,
    const float* __restrict__ ae_, unsigned short* __restrict__ Wbt,
    float* __restrict__ v_edge, int* __restrict__ hist,
    unsigned int* __restrict__ bar) {
  int b = blockIdx.x, t = threadIdx.x;
  if (b < 64) {
    Wbt[(size_t)t * 64 + b] = f2bf(W[b * HC + (t & 3) * 64 + (t >> 2)]);
  } else if (b == 64) {
    if (t < DE * HH) {
      int d = t >> 2, h = t & 3;
      float s = 0.f;
      for (int c = 0; c < CC; ++c)
        s += We[d * HC + h * CC + c] * ae_[h * CC + c];
      v_edge[t] = s;
    } else if (t < DE * HH + 64) {
      bar[t - DE * HH] = 0u;
    }
  } else {
    int idx = (b - 65) * 256 + t;
    if (idx < NN) hist[idx] = 0;
  }
}

#define EDGE_STEP(rn, un)                                              \
    {                                                                  \
      f32x2 ta, tb, xa, xb2;                                           \
      ta.x = __uint_as_float(rn.x << 16);                              \
      ta.y = __uint_as_float(rn.x & 0xffff0000u);                      \
      tb.x = __uint_as_float(rn.y << 16);                              \
      tb.y = __uint_as_float(rn.y & 0xffff0000u);                      \
      xa.x = __uint_as_float(un.x << 16);                              \
      xa.y = __uint_as_float(un.x & 0xffff0000u);                      \
      xb2.x = __uint_as_float(un.y << 16);                             \
      xb2.y = __uint_as_float(un.y & 0xffff0000u);                     \
      d01 += ta;                                                       \
      d23 += tb;                                                       \
      acc01 += ta * xa;                                                \
      acc23 += tb * xb2;                                               \
    }

// MEGA: xproj+hist -> scanA -> scanC -> edge_perm -> gat -> post1 -> final,
// one dispatch, 6 grid barriers. Phase bodies identical to R11 (which
// produced correct results); only the barrier implementation changed.
__global__ __launch_bounds__(256, 5) void k_mega(
    const float* __restrict__ node, const unsigned short* __restrict__ Wbt,
    const float* __restrict__ att_src, const float* __restrict__ att_dst,
    unsigned short* __restrict__ x16, float* __restrict__ a_src,
    float* __restrict__ a_dst, const int* __restrict__ ei,
    int* __restrict__ hist, int* __restrict__ bsum, int* __restrict__ ptr,
    int* __restrict__ cursor, const float* __restrict__ eatt,
    const float* __restrict__ v_edge, uint4* __restrict__ recs,
    uint2* __restrict__ t_lin, float* __restrict__ out_acc,
    float* __restrict__ rinv, const int* __restrict__ batch,
    const float* __restrict__ bias, float* __restrict__ p1,
    float* __restrict__ p2, int* __restrict__ gcnt,
    const float* __restrict__ gns, const float* __restrict__ gnw,
    const float* __restrict__ gnb, float* __restrict__ y,
    float* __restrict__ att_out, unsigned int* __restrict__ bar) {
  __shared__ unsigned short xs[16][260];
  __shared__ float lss[4][16][4], lsd[4][16][4];
  __shared__ int sA[256], sB[256];
  __shared__ float vsh[DE * HH];
  __shared__ float l1[4][64], l2[4][64];
  const int tid = threadIdx.x;
  const int bid = blockIdx.x;
  const int lane = tid & 63;
  const int w = tid >> 6;

  // ---------- P0: xproj + fused hist ----------
  {
    int m = lane & 15, quad = lane >> 4;
    for (int tile = bid; tile < NN / 16; tile += MB) {
      { int e = tile * 256 + tid; atomicAdd(&hist[ei[EE + e]], 1); }
      int m0 = tile * 16;
      const float* arow = node + (size_t)(m0 + m) * CC + quad * 8;
      float4 af0 = *(const float4*)(arow);
      float4 af1 = *(const float4*)(arow + 4);
      float4 af2 = *(const float4*)(arow + 32);
      float4 af3 = *(const float4*)(arow + 36);
      short8 a0 = {(short)f2bf(af0.x), (short)f2bf(af0.y), (short)f2bf(af0.z),
                   (short)f2bf(af0.w), (short)f2bf(af1.x), (short)f2bf(af1.y),
                   (short)f2bf(af1.z), (short)f2bf(af1.w)};
      short8 a1 = {(short)f2bf(af2.x), (short)f2bf(af2.y), (short)f2bf(af2.z),
                   (short)f2bf(af2.w), (short)f2bf(af3.x), (short)f2bf(af3.y),
                   (short)f2bf(af3.z), (short)f2bf(af3.w)};
      float sa[4] = {0, 0, 0, 0}, sd[4] = {0, 0, 0, 0};
#pragma unroll
      for (int i = 0; i < 4; ++i) {
        int tc = (w * 4 + i) * 16 + m;
        const unsigned short* bp = Wbt + (size_t)tc * 64 + quad * 8;
        short8 b0 = *(const short8*)(bp);
        short8 b1 = *(const short8*)(bp + 32);
        f32x4 acc = {0.f, 0.f, 0.f, 0.f};
        acc = __builtin_amdgcn_mfma_f32_16x16x32_bf16(a0, b0, acc, 0, 0, 0);
        acc = __builtin_amdgcn_mfma_f32_16x16x32_bf16(a1, b1, acc, 0, 0, 0);
        float us_t = att_src[(tc & 3) * CC + (tc >> 2)];
        float ud_t = att_dst[(tc & 3) * CC + (tc >> 2)];
#pragma unroll
        for (int r = 0; r < 4; ++r) {
          xs[quad * 4 + r][tc] = f2bf(acc[r]);
          sa[r] += acc[r] * us_t;
          sd[r] += acc[r] * ud_t;
        }
      }
#pragma unroll
      for (int r = 0; r < 4; ++r) {
        sa[r] += __shfl_xor(sa[r], 4);
        sa[r] += __shfl_xor(sa[r], 8);
        sd[r] += __shfl_xor(sd[r], 4);
        sd[r] += __shfl_xor(sd[r], 8);
      }
      if ((lane & 12) == 0) {
#pragma unroll
        for (int r = 0; r < 4; ++r) {
          lss[w][quad * 4 + r][lane & 3] = sa[r];
          lsd[w][quad * 4 + r][lane & 3] = sd[r];
        }
      }
      __syncthreads();
      if (tid < 64) {
        int row = tid >> 2, h = tid & 3;
        a_src[(size_t)(m0 + row) * 4 + h] =
            lss[0][row][h] + lss[1][row][h] + lss[2][row][h] + lss[3][row][h];
        a_dst[(size_t)(m0 + row) * 4 + h] =
            lsd[0][row][h] + lsd[1][row][h] + lsd[2][row][h] + lsd[3][row][h];
      }
      {
        int row = tid >> 4, seg = tid & 15;
        const unsigned short* xr = &xs[0][0] + row * 260 + seg * 16;
        uint2 lo = *(const uint2*)(xr);
        uint2 hi = *(const uint2*)(xr + 4);
        uint4 o;
        o.x = lo.x; o.y = lo.y; o.z = hi.x; o.w = hi.y;
        uint4* xg = (uint4*)(x16 + (size_t)m0 * HC);
        xg[row * 32 + seg * 2] = o;
        uint2 lo2 = *(const uint2*)(xr + 8);
        uint2 hi2 = *(const uint2*)(xr + 12);
        uint4 o2;
        o2.x = lo2.x; o2.y = lo2.y; o2.z = hi2.x; o2.w = hi2.y;
        xg[row * 32 + seg * 2 + 1] = o2;
      }
      __syncthreads();  // protect xs/lss reuse across grid-stride iterations
    }
  }
  grid_sync(bar);

  // ---------- P1: scanA ----------
  for (int c = bid; c < NB; c += MB) {
    int idx = c * 256 + tid;
    sA[tid] = (idx < NN) ? hist[idx] : 0;
    __syncthreads();
    for (int d = 128; d; d >>= 1) {
      if (tid < d) sA[tid] += sA[tid + d];
      __syncthreads();
    }
    if (tid == 0) bsum[c] = sA[0];
    __syncthreads();
  }
  grid_sync(bar);

  // ---------- P2: scanC ----------
  for (int c = bid; c < NB; c += MB) {
    sB[tid] = (tid < NB) ? bsum[tid] : 0;
    __syncthreads();
    for (int d = 1; d < 256; d <<= 1) {
      int u = (tid >= d) ? sB[tid - d] : 0;
      __syncthreads();
      sB[tid] += u;
      __syncthreads();
    }
    int boffv = sB[c] - bsum[c];
    if (c == NB - 1 && tid == 0) ptr[NN] = sB[NB - 1];
    int idx = c * 256 + tid;
    int v = (idx < NN) ? hist[idx] : 0;
    sA[tid] = v;
    __syncthreads();
    for (int d = 1; d < 256; d <<= 1) {
      int u = (tid >= d) ? sA[tid - d] : 0;
      __syncthreads();
      sA[tid] += u;
      __syncthreads();
    }
    if (idx < NN) {
      int p = boffv + sA[tid] - v;
      ptr[idx] = p;
      cursor[idx] = p;
    }
    __syncthreads();
  }
  grid_sync(bar);

  // ---------- P3: edge_perm (chunked 2 edges/thread, atomics late) ----------
  if (tid < DE * HH) vsh[tid] = v_edge[tid];
  __syncthreads();
  for (int vb = bid; vb < (EE + 511) / 512; vb += MB) {
    int e0 = vb * 512 + tid;            // always < EE (1562*512+255 < 800000)
    int e1 = e0 + 256;
    bool has1 = (e1 < EE);
    int e1c = has1 ? e1 : e0;
    int sn0 = ei[e0], dn0 = ei[EE + e0];
    int sn1 = ei[e1c], dn1 = ei[EE + e1c];
    float4 as0 = *(const float4*)(a_src + (size_t)sn0 * 4);
    float4 ad0 = *(const float4*)(a_dst + (size_t)dn0 * 4);
    float4 as1 = *(const float4*)(a_src + (size_t)sn1 * 4);
    float4 ad1 = *(const float4*)(a_dst + (size_t)dn1 * 4);
    const float4* ea0 = (const float4*)(eatt + (size_t)e0 * DE);
    const float4* ea1 = (const float4*)(eatt + (size_t)e1c * DE);
    float ae0[4] = {0, 0, 0, 0}, ae1[4] = {0, 0, 0, 0};
#pragma unroll
    for (int dd = 0; dd < 4; ++dd) {
      float4 ev0 = ea0[dd];
      float4 ev1 = ea1[dd];
      float evs0[4] = {ev0.x, ev0.y, ev0.z, ev0.w};
      float evs1[4] = {ev1.x, ev1.y, ev1.z, ev1.w};
#pragma unroll
      for (int jj = 0; jj < 4; ++jj) {
        int d = dd * 4 + jj;
#pragma unroll
        for (int h = 0; h < 4; ++h) {
          ae0[h] += evs0[jj] * vsh[d * 4 + h];
          ae1[h] += evs1[jj] * vsh[d * 4 + h];
        }
      }
    }
    float p0 = __expf(lrelu(as0.x + ad0.x + ae0[0]));
    float p1v = __expf(lrelu(as0.y + ad0.y + ae0[1]));
    float p2v = __expf(lrelu(as0.z + ad0.z + ae0[2]));
    float p3 = __expf(lrelu(as0.w + ad0.w + ae0[3]));
    float q0 = __expf(lrelu(as1.x + ad1.x + ae1[0]));
    float q1 = __expf(lrelu(as1.y + ad1.y + ae1[1]));
    float q2 = __expf(lrelu(as1.z + ad1.z + ae1[2]));
    float q3 = __expf(lrelu(as1.w + ad1.w + ae1[3]));
    uint2 tl0, tl1;
    tl0.x = (unsigned int)f2bf(p0) | ((unsigned int)f2bf(p1v) << 16);
    tl0.y = (unsigned int)f2bf(p2v) | ((unsigned int)f2bf(p3) << 16);
    tl1.x = (unsigned int)f2bf(q0) | ((unsigned int)f2bf(q1) << 16);
    tl1.y = (unsigned int)f2bf(q2) | ((unsigned int)f2bf(q3) << 16);
    t_lin[e0] = tl0;
    if (has1) t_lin[e1] = tl1;
    int pos0 = atomicAdd(&cursor[dn0], 1);
    int pos1 = has1 ? atomicAdd(&cursor[dn1], 1) : 0;
    uint4 rec0;
    rec0.x = tl0.x; rec0.y = tl0.y;
    rec0.z = (unsigned int)sn0 << 9;  // byte offset: sn * HC * 2
    rec0.w = (unsigned int)e0;
    recs[pos0] = rec0;
    if (has1) {
      uint4 rec1;
      rec1.x = tl1.x; rec1.y = tl1.y;
      rec1.z = (unsigned int)sn1 << 9;
      rec1.w = (unsigned int)e1;
      recs[pos1] = rec1;
    }
  }
  grid_sync(bar);

  // ---------- P4: gat ----------
  for (int vb = bid; vb < NN / 4; vb += MB) {
    int v = vb * 4 + w;
    int start = __builtin_amdgcn_readfirstlane(ptr[v]);
    int end = __builtin_amdgcn_readfirstlane(ptr[v + 1]);
    f32x2 d01 = {0.f, 0.f}, d23 = {0.f, 0.f};
    f32x2 acc01 = {0.f, 0.f}, acc23 = {0.f, 0.f};
    const char* xbase = (const char*)x16;
    unsigned int lane8 = (unsigned int)lane * 8u;
    int j = start;
#pragma unroll 2
    for (; j + 4 <= end; j += 4) {
      uint4 r0 = recs[j];
      uint4 r1 = recs[j + 1];
      uint4 r2 = recs[j + 2];
      uint4 r3 = recs[j + 3];
      uint2 u0 = *(const uint2*)(xbase + (r0.z + lane8));
      uint2 u1 = *(const uint2*)(xbase + (r1.z + lane8));
      uint2 u2 = *(const uint2*)(xbase + (r2.z + lane8));
      uint2 u3 = *(const uint2*)(xbase + (r3.z + lane8));
      EDGE_STEP(r0, u0)
      EDGE_STEP(r1, u1)
      EDGE_STEP(r2, u2)
      EDGE_STEP(r3, u3)
    }
    for (; j < end; ++j) {
      uint4 rec = recs[j];
      uint2 u = *(const uint2*)(xbase + (rec.z + lane8));
      EDGE_STEP(rec, u)
    }
    float r0 = 1.f / (d01.x + 1e-16f), r1 = 1.f / (d01.y + 1e-16f);
    float r2 = 1.f / (d23.x + 1e-16f), r3 = 1.f / (d23.y + 1e-16f);
    out_acc[(size_t)v * CC + lane] =
        0.25f * (r0 * acc01.x + r1 * acc01.y + r2 * acc23.x + r3 * acc23.y);
    if (lane == 0)
      *(float4*)(rinv + (size_t)v * 4) = make_float4(r0, r1, r2, r3);
  }
  grid_sync(bar);

  // ---------- P5: post1 (statsA + att) ----------
  for (int b = bid; b < GG * SB + (EE + 255) / 256; b += MB) {
    if (b < GG * SB) {
      int g = b / SB, sb = b % SB;
      int lo = 0, hi = NN;
      while (lo < hi) {
        int mid = (lo + hi) >> 1;
        if (batch[mid] < g) lo = mid + 1; else hi = mid;
      }
      int start = lo;
      hi = NN;
      while (lo < hi) {
        int mid = (lo + hi) >> 1;
        if (batch[mid] < g + 1) lo = mid + 1; else hi = mid;
      }
      int end = lo;
      int cnt = end - start;
      if (sb == 0 && tid == 0) gcnt[g] = cnt;
      int chunk = (cnt + SB - 1) / SB;
      int c0 = start + sb * chunk;
      int c1 = min(c0 + chunk, end);
      float bv = bias[lane];
      float s1 = 0.f, s2 = 0.f;
      for (int n = c0 + w; n < c1; n += 4) {
        float v = out_acc[(size_t)n * CC + lane] + bv;
        s1 += v;
        s2 += v * v;
      }
      l1[w][lane] = s1;
      l2[w][lane] = s2;
      __syncthreads();
      if (w == 0) {
        s1 = l1[0][lane] + l1[1][lane] + l1[2][lane] + l1[3][lane];
        s2 = l2[0][lane] + l2[1][lane] + l2[2][lane] + l2[3][lane];
        p1[(size_t)(g * SB + sb) * 64 + lane] = s1;
        p2[(size_t)(g * SB + sb) * 64 + lane] = s2;
      }
      __syncthreads();
    } else {
      int e = (b - GG * SB) * 256 + tid;
      if (e < EE) {
        uint2 tl = t_lin[e];
        int dn = ei[EE + e];
        float4 r = *(const float4*)(rinv + (size_t)dn * 4);
        float t0 = __uint_as_float(tl.x << 16);
        float t1 = __uint_as_float(tl.x & 0xffff0000u);
        float t2 = __uint_as_float(tl.y << 16);
        float t3 = __uint_as_float(tl.y & 0xffff0000u);
        *(float4*)(att_out + (size_t)e * 4) =
            make_float4(t0 * r.x, t1 * r.y, t2 * r.z, t3 * r.w);
      }
    }
  }
  grid_sync(bar);

  // ---------- P6: final (statsB fused) ----------
  for (int vb = bid; vb < NN / 4; vb += MB) {
    int n = vb * 4 + w;
    int g = batch[n];
    float s1 = 0.f, s2 = 0.f;
#pragma unroll
    for (int sb = 0; sb < SB; ++sb) {
      s1 += p1[(size_t)(g * SB + sb) * 64 + lane];
      s2 += p2[(size_t)(g * SB + sb) * 64 + lane];
    }
    float c = fmaxf((float)gcnt[g], 1.0f);
    float mean = s1 / c;
    float ms = mean * gns[lane];
    float var = s2 / c - 2.f * ms * mean + ms * ms;
    float istd = rsqrtf(var + EPSV);
    float v = out_acc[(size_t)n * CC + lane] + bias[lane];
    float o = (v - ms) * istd;
    float r = gnw[lane] * o + gnb[lane];
    y[(size_t)n * CC + lane] = fmaxf(r, 0.0f);
  }
}

#undef EDGE_STEP

extern "C" void kernel_launch(void* const* d_in, const int* in_sizes, int n_in,
                              void* d_out, int out_size, void* d_ws, size_t ws_size,
                              hipStream_t stream) {
  const float* node = (const float*)d_in[0];
  const int* ei = (const int*)d_in[1];
  const float* eatt = (const float*)d_in[2];
  const int* batch = (const int*)d_in[3];
  const float* W = (const float*)d_in[4];
  const float* We = (const float*)d_in[5];
  const float* att_src = (const float*)d_in[6];
  const float* att_dst = (const float*)d_in[7];
  const float* att_edge = (const float*)d_in[8];
  const float* bias = (const float*)d_in[9];
  const float* gnw = (const float*)d_in[10];
  const float* gnb = (const float*)d_in[11];
  const float* gns = (const float*)d_in[12];

  float* ws = (float*)d_ws;
  size_t off = 0;
  uint4* recs = (uint4*)(ws + off);  off += (size_t)EE * 4;  // 12.8 MB
  float* a_src = ws + off;    off += (size_t)NN * HH;
  float* a_dst = ws + off;    off += (size_t)NN * HH;
  float* v_edge = ws + off;   off += 64;
  float* out_acc = ws + off;  off += (size_t)NN * CC;
  float* rinv = ws + off;     off += (size_t)NN * HH;     // 0.8 MB
  float* p1 = ws + off;       off += (size_t)GG * SB * 64; // 256 KB
  float* p2 = ws + off;       off += (size_t)GG * SB * 64; // 256 KB
  uint2* t_lin = (uint2*)(ws + off);
  off += (size_t)EE * 2;                                  // 6.4 MB
  unsigned short* x16 = (unsigned short*)(ws + off);
  off += (size_t)NN * HC / 2;                             // 12.8M ushort
  unsigned short* Wbt = (unsigned short*)(ws + off);
  off += (size_t)CC * HC / 2;                             // 16K ushort
  int* iws = (int*)(ws + off);
  size_t ioff = 0;
  int* hist = iws + ioff;     ioff += NN;
  int* ptr = iws + ioff;      ioff += NN + 1;
  int* cursor = iws + ioff;   ioff += NN;
  int* bsum = iws + ioff;     ioff += NB;
  int* gcnt = iws + ioff;     ioff += GG;
  ioff = (ioff + 31) & ~31ull;                            // 128B align bar
  unsigned int* bar = (unsigned int*)(iws + ioff); ioff += 64;

  float* y_out = (float*)d_out;
  float* att_out = (float*)d_out + (size_t)NN * CC;

  // 2 dispatches. R11 proved mega correctness; this round fixes the barrier
  // (read-only polling, split lines) that caused the 1146us stall.
  k_prep<<<261, 256, 0, stream>>>(W, We, att_edge, Wbt, v_edge, hist, bar);
  k_mega<<<MB, 256, 0, stream>>>(node, Wbt, att_src, att_dst, x16, a_src,
                                 a_dst, ei, hist, bsum, ptr, cursor, eatt,
                                 v_edge, recs, t_lin, out_acc, rinv, batch,
                                 bias, p1, p2, gcnt, gns, gnw, gnb, y_out,
                                 att_out, bar);
}

// Round 13
// 288.970 us; speedup vs baseline: 4.2707x; 3.0308x over previous
//
#include <hip/hip_runtime.h>
#include <math.h>

#define NN 50000
#define EE 800000
#define HH 4
#define CC 64
#define DE 16
#define GG 64
#define HC 256          // H*C
#define NEG 0.2f
#define EPSV 1e-5f
#define NB 196          // scan blocks: 196*256 = 50176 >= NN
#define SB 16           // stats sub-blocks per group

typedef __attribute__((ext_vector_type(8))) short short8;
typedef __attribute__((ext_vector_type(4))) float f32x4;
typedef __attribute__((ext_vector_type(2))) float f32x2;

__device__ __forceinline__ unsigned short f2bf(float f) {
  unsigned int x = __float_as_uint(f);
  unsigned int r = (x + 0x7fff + ((x >> 16) & 1)) >> 16;  // round-nearest-even
  return (unsigned short)r;
}
__device__ __forceinline__ float lrelu(float a) {
  return fmaxf(a, 0.f) + NEG * fminf(a, 0.f);
}

// NOTE (R11/R12 lesson): single-kernel phase fusion with device-wide barriers
// is structurally losing on gfx950 — agent-scope fences must write back +
// invalidate the 8 non-coherent XCD L2s, costing ~100us/barrier in flush +
// cold-cache refetch (WRITE_SIZE +125MB, FETCH +90MB measured). Multi-dispatch
// with ~8us gaps is the cheaper synchronization primitive. Reverted to the
// proven R10 8-dispatch structure.

// K0: blocks 0..63: Wbt transpose. block 64: v_edge. blocks 65..260: zero hist.
__global__ __launch_bounds__(256) void k_prep(
    const float* __restrict__ W, const float* __restrict__ We,
    const float* __restrict__ ae_, unsigned short* __restrict__ Wbt,
    float* __restrict__ v_edge, int* __restrict__ hist) {
  int b = blockIdx.x, t = threadIdx.x;
  if (b < 64) {
    Wbt[(size_t)t * 64 + b] = f2bf(W[b * HC + (t & 3) * 64 + (t >> 2)]);
  } else if (b == 64) {
    if (t < DE * HH) {
      int d = t >> 2, h = t & 3;
      float s = 0.f;
      for (int c = 0; c < CC; ++c)
        s += We[d * HC + h * CC + c] * ae_[h * CC + c];
      v_edge[t] = s;
    }
  } else {
    int idx = (b - 65) * 256 + t;
    if (idx < NN) hist[idx] = 0;
  }
}

// K1: MFMA projection + fused dst histogram. NEW: the histogram atomic's
// return value (previously discarded) IS the edge's rank within its dst
// bucket — store it so k_edge_perm can compute its scatter slot WITHOUT an
// atomic round-trip (pos = ptr[dn] + rank[e]).
__global__ __launch_bounds__(256) void k_xproj(
    const float* __restrict__ node, const unsigned short* __restrict__ Wbt,
    const float* __restrict__ att_src, const float* __restrict__ att_dst,
    unsigned short* __restrict__ x16, float* __restrict__ a_src,
    float* __restrict__ a_dst, const int* __restrict__ ei,
    int* __restrict__ hist, int* __restrict__ rank) {
  {
    int e = blockIdx.x * 256 + threadIdx.x;  // EE == gridDim*256 exactly
    rank[e] = atomicAdd(&hist[ei[EE + e]], 1);
  }
  int lane = threadIdx.x & 63;
  int w = threadIdx.x >> 6;
  int m = lane & 15, quad = lane >> 4;
  int m0 = blockIdx.x * 16;
  __shared__ unsigned short xs[16][260];  // +4 pad: quad rows hit distinct banks
  const float* arow = node + (size_t)(m0 + m) * CC + quad * 8;
  float4 af0 = *(const float4*)(arow);
  float4 af1 = *(const float4*)(arow + 4);
  float4 af2 = *(const float4*)(arow + 32);
  float4 af3 = *(const float4*)(arow + 36);
  short8 a0 = {(short)f2bf(af0.x), (short)f2bf(af0.y), (short)f2bf(af0.z),
               (short)f2bf(af0.w), (short)f2bf(af1.x), (short)f2bf(af1.y),
               (short)f2bf(af1.z), (short)f2bf(af1.w)};
  short8 a1 = {(short)f2bf(af2.x), (short)f2bf(af2.y), (short)f2bf(af2.z),
               (short)f2bf(af2.w), (short)f2bf(af3.x), (short)f2bf(af3.y),
               (short)f2bf(af3.z), (short)f2bf(af3.w)};
  float sa[4] = {0, 0, 0, 0}, sd[4] = {0, 0, 0, 0};
#pragma unroll
  for (int i = 0; i < 4; ++i) {
    int t = (w * 4 + i) * 16 + m;
    const unsigned short* bp = Wbt + (size_t)t * 64 + quad * 8;
    short8 b0 = *(const short8*)(bp);
    short8 b1 = *(const short8*)(bp + 32);
    f32x4 acc = {0.f, 0.f, 0.f, 0.f};
    acc = __builtin_amdgcn_mfma_f32_16x16x32_bf16(a0, b0, acc, 0, 0, 0);
    acc = __builtin_amdgcn_mfma_f32_16x16x32_bf16(a1, b1, acc, 0, 0, 0);
    float us_t = att_src[(t & 3) * CC + (t >> 2)];
    float ud_t = att_dst[(t & 3) * CC + (t >> 2)];
#pragma unroll
    for (int r = 0; r < 4; ++r) {
      xs[quad * 4 + r][t] = f2bf(acc[r]);
      sa[r] += acc[r] * us_t;
      sd[r] += acc[r] * ud_t;
    }
  }
  __shared__ float lss[4][16][4], lsd[4][16][4];
#pragma unroll
  for (int r = 0; r < 4; ++r) {
    sa[r] += __shfl_xor(sa[r], 4);
    sa[r] += __shfl_xor(sa[r], 8);
    sd[r] += __shfl_xor(sd[r], 4);
    sd[r] += __shfl_xor(sd[r], 8);
  }
  if ((lane & 12) == 0) {
#pragma unroll
    for (int r = 0; r < 4; ++r) {
      lss[w][quad * 4 + r][lane & 3] = sa[r];
      lsd[w][quad * 4 + r][lane & 3] = sd[r];
    }
  }
  __syncthreads();
  int t = threadIdx.x;
  if (t < 64) {
    int row = t >> 2, h = t & 3;
    a_src[(size_t)(m0 + row) * 4 + h] =
        lss[0][row][h] + lss[1][row][h] + lss[2][row][h] + lss[3][row][h];
    a_dst[(size_t)(m0 + row) * 4 + h] =
        lsd[0][row][h] + lsd[1][row][h] + lsd[2][row][h] + lsd[3][row][h];
  }
  {
    int row = t >> 4, seg = t & 15;
    const unsigned short* xr = &xs[0][0] + row * 260 + seg * 16;
    uint2 lo = *(const uint2*)(xr);
    uint2 hi = *(const uint2*)(xr + 4);
    uint4 o;
    o.x = lo.x; o.y = lo.y; o.z = hi.x; o.w = hi.y;
    uint4* xg = (uint4*)(x16 + (size_t)m0 * HC);
    xg[row * 32 + seg * 2] = o;
    uint2 lo2 = *(const uint2*)(xr + 8);
    uint2 hi2 = *(const uint2*)(xr + 12);
    uint4 o2;
    o2.x = lo2.x; o2.y = lo2.y; o2.z = hi2.x; o2.w = hi2.y;
    xg[row * 32 + seg * 2 + 1] = o2;
  }
}

// K3a: coalesced per-block sums of the histogram.
__global__ __launch_bounds__(256) void k_scanA(
    const int* __restrict__ hist, int* __restrict__ bsum) {
  __shared__ int s[256];
  int t = threadIdx.x;
  int idx = blockIdx.x * 256 + t;
  s[t] = (idx < NN) ? hist[idx] : 0;
  __syncthreads();
  for (int d = 128; d; d >>= 1) {
    if (t < d) s[t] += s[t + d];
    __syncthreads();
  }
  if (t == 0) bsum[blockIdx.x] = s[0];
}

// K3c: fused block-offset scan + per-block exclusive scan -> ptr.
// (cursor no longer needed: slots come from ptr[dn] + rank[e].)
__global__ __launch_bounds__(256) void k_scanC(
    const int* __restrict__ hist, const int* __restrict__ bsum,
    int* __restrict__ ptr) {
  __shared__ int sb_[256];
  __shared__ int s[256];
  int t = threadIdx.x;
  sb_[t] = (t < NB) ? bsum[t] : 0;
  __syncthreads();
  for (int d = 1; d < 256; d <<= 1) {
    int u = (t >= d) ? sb_[t - d] : 0;
    __syncthreads();
    sb_[t] += u;
    __syncthreads();
  }
  int boffv = sb_[blockIdx.x] - bsum[blockIdx.x];  // exclusive prefix
  if (blockIdx.x == NB - 1 && t == 0) ptr[NN] = sb_[NB - 1];
  int idx = blockIdx.x * 256 + t;
  int v = (idx < NN) ? hist[idx] : 0;
  s[t] = v;
  __syncthreads();
  for (int d = 1; d < 256; d <<= 1) {
    int u = (t >= d) ? s[t - d] : 0;
    __syncthreads();
    s[t] += u;
    __syncthreads();
  }
  if (idx < NN) ptr[idx] = boffv + s[t] - v;
}

// K4: fused edge pass, chunked 2 edges/thread. NO ATOMIC: scatter slot is
// ptr[dn] + rank[e] — rank comes coalesced from k_xproj's histogram pass,
// ptr[dn] is a random 4B gather into a 200KB L2-resident array. Both are
// plain loads issuable alongside the a_src/a_dst gathers, removing the
// ~600cy atomic RMW round-trip from the per-edge chain.
__global__ __launch_bounds__(256) void k_edge_perm(
    const float* __restrict__ edge_attr, const int* __restrict__ ei,
    const float* __restrict__ a_src, const float* __restrict__ a_dst,
    const float* __restrict__ v_edge, const int* __restrict__ ptr,
    const int* __restrict__ rank, uint4* __restrict__ recs,
    uint2* __restrict__ t_lin) {
  __shared__ float vs[DE * HH];
  int t = threadIdx.x;
  if (t < DE * HH) vs[t] = v_edge[t];
  __syncthreads();
  int e0 = blockIdx.x * 512 + t;
  int e1 = e0 + 256;
  if (e0 >= EE) return;
  bool has1 = (e1 < EE);
  int e1c = has1 ? e1 : e0;
  int sn0 = ei[e0], dn0 = ei[EE + e0];
  int sn1 = ei[e1c], dn1 = ei[EE + e1c];
  int rk0 = rank[e0];
  int rk1 = rank[e1c];
  int base0 = ptr[dn0];
  int base1 = ptr[dn1];
  float4 as0 = *(const float4*)(a_src + (size_t)sn0 * 4);
  float4 ad0 = *(const float4*)(a_dst + (size_t)dn0 * 4);
  float4 as1 = *(const float4*)(a_src + (size_t)sn1 * 4);
  float4 ad1 = *(const float4*)(a_dst + (size_t)dn1 * 4);
  const float4* ea0 = (const float4*)(edge_attr + (size_t)e0 * DE);
  const float4* ea1 = (const float4*)(edge_attr + (size_t)e1c * DE);
  float ae0[4] = {0, 0, 0, 0}, ae1[4] = {0, 0, 0, 0};
#pragma unroll
  for (int dd = 0; dd < 4; ++dd) {
    float4 ev0 = ea0[dd];
    float4 ev1 = ea1[dd];
    float evs0[4] = {ev0.x, ev0.y, ev0.z, ev0.w};
    float evs1[4] = {ev1.x, ev1.y, ev1.z, ev1.w};
#pragma unroll
    for (int jj = 0; jj < 4; ++jj) {
      int d = dd * 4 + jj;
#pragma unroll
      for (int h = 0; h < 4; ++h) {
        ae0[h] += evs0[jj] * vs[d * 4 + h];
        ae1[h] += evs1[jj] * vs[d * 4 + h];
      }
    }
  }
  float p0 = __expf(lrelu(as0.x + ad0.x + ae0[0]));
  float p1 = __expf(lrelu(as0.y + ad0.y + ae0[1]));
  float p2 = __expf(lrelu(as0.z + ad0.z + ae0[2]));
  float p3 = __expf(lrelu(as0.w + ad0.w + ae0[3]));
  float q0 = __expf(lrelu(as1.x + ad1.x + ae1[0]));
  float q1 = __expf(lrelu(as1.y + ad1.y + ae1[1]));
  float q2 = __expf(lrelu(as1.z + ad1.z + ae1[2]));
  float q3 = __expf(lrelu(as1.w + ad1.w + ae1[3]));
  uint2 tl0, tl1;
  tl0.x = (unsigned int)f2bf(p0) | ((unsigned int)f2bf(p1) << 16);
  tl0.y = (unsigned int)f2bf(p2) | ((unsigned int)f2bf(p3) << 16);
  tl1.x = (unsigned int)f2bf(q0) | ((unsigned int)f2bf(q1) << 16);
  tl1.y = (unsigned int)f2bf(q2) | ((unsigned int)f2bf(q3) << 16);
  t_lin[e0] = tl0;
  if (has1) t_lin[e1] = tl1;
  uint4 rec0;
  rec0.x = tl0.x; rec0.y = tl0.y;
  rec0.z = (unsigned int)sn0 << 9;  // byte offset: sn * HC * 2
  rec0.w = (unsigned int)e0;
  recs[base0 + rk0] = rec0;
  if (has1) {
    uint4 rec1;
    rec1.x = tl1.x; rec1.y = tl1.y;
    rec1.z = (unsigned int)sn1 << 9;
    rec1.w = (unsigned int)e1;
    recs[base1 + rk1] = rec1;
  }
}

// K5: one wave per dst node (unchanged).
__global__ __launch_bounds__(256) void k_gat(
    const int* __restrict__ ptr, const uint4* __restrict__ recs,
    const unsigned short* __restrict__ x16, float* __restrict__ out_acc,
    float* __restrict__ rinv) {
  int lane = threadIdx.x & 63;
  int w = threadIdx.x >> 6;
  int v = blockIdx.x * 4 + w;
  int start = __builtin_amdgcn_readfirstlane(ptr[v]);
  int end = __builtin_amdgcn_readfirstlane(ptr[v + 1]);
  f32x2 d01 = {0.f, 0.f}, d23 = {0.f, 0.f};
  f32x2 acc01 = {0.f, 0.f}, acc23 = {0.f, 0.f};
  const char* xbase = (const char*)x16;
  unsigned int lane8 = (unsigned int)lane * 8u;
  int j = start;
#pragma unroll 2
  for (; j + 4 <= end; j += 4) {
    uint4 r0 = recs[j];
    uint4 r1 = recs[j + 1];
    uint4 r2 = recs[j + 2];
    uint4 r3 = recs[j + 3];
    uint2 u0 = *(const uint2*)(xbase + (r0.z + lane8));
    uint2 u1 = *(const uint2*)(xbase + (r1.z + lane8));
    uint2 u2 = *(const uint2*)(xbase + (r2.z + lane8));
    uint2 u3 = *(const uint2*)(xbase + (r3.z + lane8));
#define EDGE_STEP(rn, un)                                              \
    {                                                                  \
      f32x2 ta, tb, xa, xb2;                                           \
      ta.x = __uint_as_float(rn.x << 16);                              \
      ta.y = __uint_as_float(rn.x & 0xffff0000u);                      \
      tb.x = __uint_as_float(rn.y << 16);                              \
      tb.y = __uint_as_float(rn.y & 0xffff0000u);                      \
      xa.x = __uint_as_float(un.x << 16);                              \
      xa.y = __uint_as_float(un.x & 0xffff0000u);                      \
      xb2.x = __uint_as_float(un.y << 16);                             \
      xb2.y = __uint_as_float(un.y & 0xffff0000u);                     \
      d01 += ta;                                                       \
      d23 += tb;                                                       \
      acc01 += ta * xa;                                                \
      acc23 += tb * xb2;                                               \
    }
    EDGE_STEP(r0, u0)
    EDGE_STEP(r1, u1)
    EDGE_STEP(r2, u2)
    EDGE_STEP(r3, u3)
  }
  for (; j < end; ++j) {
    uint4 rec = recs[j];
    uint2 u = *(const uint2*)(xbase + (rec.z + lane8));
    EDGE_STEP(rec, u)
  }
#undef EDGE_STEP
  float r0 = 1.f / (d01.x + 1e-16f), r1 = 1.f / (d01.y + 1e-16f);
  float r2 = 1.f / (d23.x + 1e-16f), r3 = 1.f / (d23.y + 1e-16f);
  out_acc[(size_t)v * CC + lane] =
      0.25f * (r0 * acc01.x + r1 * acc01.y + r2 * acc23.x + r3 * acc23.y);
  if (lane == 0)
    *(float4*)(rinv + (size_t)v * 4) = make_float4(r0, r1, r2, r3);
}

// K6: FUSED statsA + att. statsA (g,sb=0) block also records the group count
// for the statsB math fused into k_final.
__global__ __launch_bounds__(256) void k_post1(
    const int* __restrict__ batch, const float* __restrict__ out_acc,
    const float* __restrict__ bias, float* __restrict__ p1,
    float* __restrict__ p2, int* __restrict__ gcnt,
    const int* __restrict__ ei, const uint2* __restrict__ t_lin,
    const float* __restrict__ rinv, float* __restrict__ att_out) {
  int b = blockIdx.x;
  if (b < GG * SB) {
    int g = b / SB, sb = b % SB;
    int lane = threadIdx.x & 63;
    int w = threadIdx.x >> 6;
    int lo = 0, hi = NN;
    while (lo < hi) {
      int mid = (lo + hi) >> 1;
      if (batch[mid] < g) lo = mid + 1; else hi = mid;
    }
    int start = lo;
    hi = NN;
    while (lo < hi) {
      int mid = (lo + hi) >> 1;
      if (batch[mid] < g + 1) lo = mid + 1; else hi = mid;
    }
    int end = lo;
    int cnt = end - start;
    if (sb == 0 && threadIdx.x == 0) gcnt[g] = cnt;
    int chunk = (cnt + SB - 1) / SB;
    int c0 = start + sb * chunk;
    int c1 = min(c0 + chunk, end);
    float bv = bias[lane];
    float s1 = 0.f, s2 = 0.f;
    for (int n = c0 + w; n < c1; n += 4) {
      float v = out_acc[(size_t)n * CC + lane] + bv;
      s1 += v;
      s2 += v * v;
    }
    __shared__ float l1[4][64], l2[4][64];
    l1[w][lane] = s1;
    l2[w][lane] = s2;
    __syncthreads();
    if (w == 0) {
      s1 = l1[0][lane] + l1[1][lane] + l1[2][lane] + l1[3][lane];
      s2 = l2[0][lane] + l2[1][lane] + l2[2][lane] + l2[3][lane];
      p1[(size_t)(g * SB + sb) * 64 + lane] = s1;
      p2[(size_t)(g * SB + sb) * 64 + lane] = s2;
    }
  } else {
    int e = (b - GG * SB) * 256 + threadIdx.x;
    if (e >= EE) return;
    uint2 tl = t_lin[e];
    int dn = ei[EE + e];
    float4 r = *(const float4*)(rinv + (size_t)dn * 4);
    float t0 = __uint_as_float(tl.x << 16);
    float t1 = __uint_as_float(tl.x & 0xffff0000u);
    float t2 = __uint_as_float(tl.y << 16);
    float t3 = __uint_as_float(tl.y & 0xffff0000u);
    *(float4*)(att_out + (size_t)e * 4) =
        make_float4(t0 * r.x, t1 * r.y, t2 * r.z, t3 * r.w);
  }
}

// K7: normalize + affine + relu, with statsB fused (bit-identical math).
__global__ __launch_bounds__(256) void k_final(
    const int* __restrict__ batch, const float* __restrict__ out_acc,
    const float* __restrict__ bias, const float* __restrict__ p1,
    const float* __restrict__ p2, const int* __restrict__ gcnt,
    const float* __restrict__ gns, const float* __restrict__ gnw,
    const float* __restrict__ gnb, float* __restrict__ y) {
  int lane = threadIdx.x & 63;
  int n = blockIdx.x * 4 + (threadIdx.x >> 6);
  int g = batch[n];
  float s1 = 0.f, s2 = 0.f;
#pragma unroll
  for (int sb = 0; sb < SB; ++sb) {
    s1 += p1[(size_t)(g * SB + sb) * 64 + lane];
    s2 += p2[(size_t)(g * SB + sb) * 64 + lane];
  }
  float c = fmaxf((float)gcnt[g], 1.0f);
  float mean = s1 / c;
  float ms = mean * gns[lane];
  float var = s2 / c - 2.f * ms * mean + ms * ms;
  float istd = rsqrtf(var + EPSV);
  float v = out_acc[(size_t)n * CC + lane] + bias[lane];
  float o = (v - ms) * istd;
  float r = gnw[lane] * o + gnb[lane];
  y[(size_t)n * CC + lane] = fmaxf(r, 0.0f);
}

extern "C" void kernel_launch(void* const* d_in, const int* in_sizes, int n_in,
                              void* d_out, int out_size, void* d_ws, size_t ws_size,
                              hipStream_t stream) {
  const float* node = (const float*)d_in[0];
  const int* ei = (const int*)d_in[1];
  const float* eatt = (const float*)d_in[2];
  const int* batch = (const int*)d_in[3];
  const float* W = (const float*)d_in[4];
  const float* We = (const float*)d_in[5];
  const float* att_src = (const float*)d_in[6];
  const float* att_dst = (const float*)d_in[7];
  const float* att_edge = (const float*)d_in[8];
  const float* bias = (const float*)d_in[9];
  const float* gnw = (const float*)d_in[10];
  const float* gnb = (const float*)d_in[11];
  const float* gns = (const float*)d_in[12];

  float* ws = (float*)d_ws;
  size_t off = 0;
  uint4* recs = (uint4*)(ws + off);  off += (size_t)EE * 4;  // 12.8 MB
  float* a_src = ws + off;    off += (size_t)NN * HH;
  float* a_dst = ws + off;    off += (size_t)NN * HH;
  float* v_edge = ws + off;   off += 64;
  float* out_acc = ws + off;  off += (size_t)NN * CC;
  float* rinv = ws + off;     off += (size_t)NN * HH;     // 0.8 MB
  float* p1 = ws + off;       off += (size_t)GG * SB * 64; // 256 KB
  float* p2 = ws + off;       off += (size_t)GG * SB * 64; // 256 KB
  uint2* t_lin = (uint2*)(ws + off);
  off += (size_t)EE * 2;                                  // 6.4 MB
  unsigned short* x16 = (unsigned short*)(ws + off);
  off += (size_t)NN * HC / 2;                             // 12.8M ushort
  unsigned short* Wbt = (unsigned short*)(ws + off);
  off += (size_t)CC * HC / 2;                             // 16K ushort
  int* iws = (int*)(ws + off);
  size_t ioff = 0;
  int* hist = iws + ioff;     ioff += NN;
  int* ptr = iws + ioff;      ioff += NN + 1;
  int* rank = iws + ioff;     ioff += EE;                 // 3.2 MB
  int* bsum = iws + ioff;     ioff += NB;
  int* gcnt = iws + ioff;     ioff += GG;

  float* y_out = (float*)d_out;
  float* att_out = (float*)d_out + (size_t)NN * CC;

  // 8 dispatches (proven R10 structure; mega-kernel reverted per R11/R12).
  k_prep<<<261, 256, 0, stream>>>(W, We, att_edge, Wbt, v_edge, hist);
  k_xproj<<<NN / 16, 256, 0, stream>>>(node, Wbt, att_src, att_dst, x16, a_src,
                                       a_dst, ei, hist, rank);
  k_scanA<<<NB, 256, 0, stream>>>(hist, bsum);
  k_scanC<<<NB, 256, 0, stream>>>(hist, bsum, ptr);
  k_edge_perm<<<(EE + 511) / 512, 256, 0, stream>>>(eatt, ei, a_src, a_dst,
                                                    v_edge, ptr, rank, recs,
                                                    t_lin);
  k_gat<<<NN / 4, 256, 0, stream>>>(ptr, recs, x16, out_acc, rinv);
  k_post1<<<GG * SB + (EE + 255) / 256, 256, 0, stream>>>(
      batch, out_acc, bias, p1, p2, gcnt, ei, t_lin, rinv, att_out);
  k_final<<<NN / 4, 256, 0, stream>>>(batch, out_acc, bias, p1, p2, gcnt, gns,
                                      gnw, gnb, y_out);
}